// Round 5
// baseline (1174.908 us; speedup 1.0000x reference)
//
#include <hip/hip_runtime.h>
#include <stdint.h>
#include <math.h>

#define SB 256
#define SI 8
#define SCHUNK (SB*SI)
#define SORT_LDS 4096   // u64 entries = 32 KB; mean need 3072, +18 sigma margin

__constant__ int c_tri[16][6] = {
  {-1,-1,-1,-1,-1,-1},{1,0,2,-1,-1,-1},{4,0,3,-1,-1,-1},{1,4,2,1,3,4},
  {3,1,5,-1,-1,-1},{2,3,0,2,5,3},{1,4,0,1,5,4},{4,2,5,-1,-1,-1},
  {4,5,2,-1,-1,-1},{4,1,0,4,5,1},{3,2,0,3,5,2},{1,3,5,-1,-1,-1},
  {4,1,2,4,3,1},{3,0,4,-1,-1,-1},{2,0,1,-1,-1,-1},{-1,-1,-1,-1,-1,-1}};
__constant__ int c_ntri[16] = {0,1,1,2,1,2,2,1,1,2,2,1,2,1,1,0};
__constant__ int c_ea[6] = {0,0,0,1,1,2};
__constant__ int c_eb[6] = {1,2,3,2,3,3};

// ---------------- classify tets: occupancy bits + bucket count + slot stash --
__global__ void k_classify(const int4* __restrict__ tet, const float* __restrict__ sdf,
                           uint8_t* __restrict__ tetidx, int* __restrict__ bucketCnt,
                           ushort4* __restrict__ stash, int nt) {
  int t = blockIdx.x * blockDim.x + threadIdx.x;
  if (t >= nt) return;
  int4 v = tet[t];
  int ids[4] = {v.x, v.y, v.z, v.w};
  int bits = 0;
#pragma unroll
  for (int i = 0; i < 4; i++) bits |= (sdf[ids[i]] > 0.0f) ? (1 << i) : 0;
  tetidx[t] = (uint8_t)bits;
  if (c_ntri[bits] == 0) return;
  unsigned short st[4] = {0, 0, 0, 0};
  int c = 0;
#pragma unroll
  for (int e = 0; e < 6; e++) {
    int a = c_ea[e], b = c_eb[e];
    if ((((bits >> a) ^ (bits >> b)) & 1) == 0) continue;
    int va = ids[a], vb = ids[b];
    int lo = va < vb ? va : vb;
    st[c++] = (unsigned short)atomicAdd(&bucketCnt[lo], 1);
  }
  stash[t] = make_ushort4(st[0], st[1], st[2], st[3]);
}

// ---------------- block exclusive scans -------------------------------------
__device__ inline unsigned long long blkExclU64(unsigned long long val, unsigned long long* sh) {
  int tid = threadIdx.x;
  sh[tid] = val; __syncthreads();
  for (int st = 1; st < SB; st <<= 1) {
    unsigned long long add = (tid >= st) ? sh[tid - st] : 0ull;
    __syncthreads();
    sh[tid] += add;
    __syncthreads();
  }
  return sh[tid] - val;
}
__device__ inline int blkExclI32(int val, int* sh) {
  int tid = threadIdx.x;
  sh[tid] = val; __syncthreads();
  for (int st = 1; st < SB; st <<= 1) {
    int add = (tid >= st) ? sh[tid - st] : 0;
    __syncthreads();
    sh[tid] += add;
    __syncthreads();
  }
  return sh[tid] - val;
}

// tet scan: value = (ntri==1) | (ntri==2)<<32
__global__ void k_tetscan1(const uint8_t* __restrict__ tetidx, unsigned long long* __restrict__ bt, int n) {
  __shared__ unsigned long long sh[SB];
  int base = blockIdx.x * SCHUNK + threadIdx.x * SI;
  unsigned long long s = 0;
  for (int k = 0; k < SI; k++) {
    int i = base + k;
    if (i < n) {
      int nt3 = c_ntri[tetidx[i]];
      s += (nt3 == 1 ? 1ull : 0ull) + (nt3 == 2 ? (1ull << 32) : 0ull);
    }
  }
  sh[threadIdx.x] = s; __syncthreads();
  for (int st = SB / 2; st > 0; st >>= 1) {
    if (threadIdx.x < st) sh[threadIdx.x] += sh[threadIdx.x + st];
    __syncthreads();
  }
  if (threadIdx.x == 0) bt[blockIdx.x] = sh[0];
}

__global__ void k_scanblk_u64(unsigned long long* __restrict__ bt, int nb,
                              int* __restrict__ scal, int slotLo, int slotHi) {
  __shared__ unsigned long long sh[SB];
  __shared__ unsigned long long carrySh;
  if (threadIdx.x == 0) carrySh = 0;
  __syncthreads();
  for (int base = 0; base < nb; base += SB) {
    int i = base + threadIdx.x;
    unsigned long long v = (i < nb) ? bt[i] : 0ull;
    unsigned long long ex = blkExclU64(v, sh);
    unsigned long long carry = carrySh;
    if (i < nb) bt[i] = carry + ex;
    __syncthreads();
    if (threadIdx.x == SB - 1) carrySh = carry + ex + v;
    __syncthreads();
  }
  if (threadIdx.x == 0) {
    scal[slotLo] = (int)(carrySh & 0xffffffffull);
    scal[slotHi] = (int)(carrySh >> 32);
  }
}

__global__ void k_tetscan3(const uint8_t* __restrict__ tetidx, const unsigned long long* __restrict__ bt,
                           unsigned long long* __restrict__ tetRank, int n) {
  __shared__ unsigned long long sh[SB];
  int base = blockIdx.x * SCHUNK + threadIdx.x * SI;
  unsigned long long vals[SI];
  unsigned long long s = 0;
  for (int k = 0; k < SI; k++) {
    int i = base + k;
    unsigned long long v = 0;
    if (i < n) {
      int nt3 = c_ntri[tetidx[i]];
      v = (nt3 == 1 ? 1ull : 0ull) + (nt3 == 2 ? (1ull << 32) : 0ull);
    }
    vals[k] = s; s += v;
  }
  unsigned long long thrOff = blkExclU64(s, sh);
  unsigned long long off = bt[blockIdx.x] + thrOff;
  for (int k = 0; k < SI; k++) {
    int i = base + k;
    if (i < n) tetRank[i] = off + vals[k];
  }
}

__global__ void k_i32scan1(const int* __restrict__ src, int* __restrict__ bt, int n) {
  __shared__ int sh[SB];
  int base = blockIdx.x * SCHUNK + threadIdx.x * SI;
  int s = 0;
  for (int k = 0; k < SI; k++) { int i = base + k; if (i < n) s += src[i]; }
  sh[threadIdx.x] = s; __syncthreads();
  for (int st = SB / 2; st > 0; st >>= 1) {
    if (threadIdx.x < st) sh[threadIdx.x] += sh[threadIdx.x + st];
    __syncthreads();
  }
  if (threadIdx.x == 0) bt[blockIdx.x] = sh[0];
}

__global__ void k_scanblk_i32(int* __restrict__ bt, int nb, int* __restrict__ scal, int slot) {
  __shared__ int sh[SB];
  __shared__ int carrySh;
  if (threadIdx.x == 0) carrySh = 0;
  __syncthreads();
  for (int base = 0; base < nb; base += SB) {
    int i = base + threadIdx.x;
    int v = (i < nb) ? bt[i] : 0;
    int ex = blkExclI32(v, sh);
    int carry = carrySh;
    if (i < nb) bt[i] = carry + ex;
    __syncthreads();
    if (threadIdx.x == SB - 1) carrySh = carry + ex + v;
    __syncthreads();
  }
  if (threadIdx.x == 0) scal[slot] = carrySh;
}

__global__ void k_i32scan3(const int* __restrict__ src, const int* __restrict__ bt,
                           int* __restrict__ dst, int n) {
  __shared__ int sh[SB];
  int base = blockIdx.x * SCHUNK + threadIdx.x * SI;
  int vals[SI];
  int s = 0;
  for (int k = 0; k < SI; k++) {
    int i = base + k;
    int v = (i < n) ? src[i] : 0;
    vals[k] = s; s += v;
  }
  int thrOff = blkExclI32(s, sh);
  int off = bt[blockIdx.x] + thrOff;
  for (int k = 0; k < SI; k++) {
    int i = base + k;
    if (i < n) dst[i] = off + vals[k];
  }
}

// ---------------- scatter (atomic-free) --------------------------------------
// key: [63:44]=hi [43:20]=pos1 (face elem idx) [19:17]=delta [16]=has2 [15:0]=origIdxInBucket
__global__ void k_scatter(const int4* __restrict__ tet, const uint8_t* __restrict__ tetidx,
                          const unsigned long long* __restrict__ tetRank, const int* __restrict__ scal,
                          const int* __restrict__ bucketOff, const ushort4* __restrict__ stash,
                          unsigned long long* __restrict__ edges, int nt) {
  int t = blockIdx.x * blockDim.x + threadIdx.x;
  if (t >= nt) return;
  int bits = tetidx[t];
  int nt3 = c_ntri[bits];
  if (nt3 == 0) return;
  int4 v = tet[t];
  int ids[4] = {v.x, v.y, v.z, v.w};
  unsigned long long pk = tetRank[t];
  int M1 = scal[0];
  int rowElemBase = (nt3 == 1) ? 3 * (int)(pk & 0xffffffffull)
                               : 3 * M1 + 6 * (int)(pk >> 32);
  ushort4 stv = stash[t];
  unsigned short sta[4] = {stv.x, stv.y, stv.z, stv.w};
  int npos = 3 * nt3;
  int c = 0;
#pragma unroll
  for (int e = 0; e < 6; e++) {
    int a = c_ea[e], b = c_eb[e];
    if ((((bits >> a) ^ (bits >> b)) & 1) == 0) continue;
    int va = ids[a], vb = ids[b];
    int lo = va < vb ? va : vb;
    int hi = va < vb ? vb : va;
    int p1 = -1, p2 = -1;
    for (int p = 0; p < npos; p++) {
      if (c_tri[bits][p] == e) { if (p1 < 0) p1 = p; else p2 = p; }
    }
    int orig = sta[c++];
    unsigned long long key = ((unsigned long long)(unsigned)hi << 44)
                           | ((unsigned long long)(unsigned)(rowElemBase + p1) << 20)
                           | ((p2 >= 0) ? (((unsigned long long)(p2 - p1) << 17) | (1ull << 16)) : 0ull)
                           | (unsigned long long)orig;
    edges[bucketOff[lo] + orig] = key;
  }
}

// ---------------- fused: LDS sort + unique count + lookback scan + emit ------
// Block (virtual id from ticket) owns buckets [bid*SB, bid*SB+SB).
// Phases: load edges->LDS, per-bucket sort, count uniques, block scan,
// decoupled-lookback for global rank base, emit verts + ranks (LDS), dump
// ranks coalesced. Sorted edges never written back (no other consumer).
// lbState[bid]: [63:62]=tag (0=none,1=partial,2=prefix) [31:0]=value.
__global__ __launch_bounds__(SB) void k_sortemit(
    const int* __restrict__ bucketOff, const int* __restrict__ bucketCnt,
    unsigned long long* __restrict__ edges,
    const float* __restrict__ pos, const float* __restrict__ sdf,
    int* __restrict__ rankArr, float* __restrict__ out, int* __restrict__ scal,
    unsigned long long* __restrict__ lbState, int* __restrict__ ticket,
    int nv, int nblocks) {
  __shared__ unsigned long long sh[SORT_LDS];
  __shared__ int shRank[SORT_LDS];
  __shared__ int shScan[SB];
  __shared__ int shBid, shBase;
  if (threadIdx.x == 0) shBid = atomicAdd(ticket, 1);
  __syncthreads();
  int bid = shBid;
  int v0 = bid * SB;
  int vLast = v0 + SB - 1;
  if (vLast >= nv) vLast = nv - 1;
  int start = bucketOff[v0];
  int end = bucketOff[vLast] + bucketCnt[vLast];
  int cnt = end - start;
  int v = v0 + threadIdx.x;
  int n = (v < nv) ? bucketCnt[v] : 0;
  int off = (v < nv) ? bucketOff[v] : start;
  bool inLds = (cnt <= SORT_LDS);
  int u = 0;
  if (inLds) {
    for (int i = threadIdx.x; i < cnt; i += SB) sh[i] = edges[start + i];
    __syncthreads();
    if (n > 0) {
      unsigned long long* a = sh + (off - start);
      for (int j = 1; j < n; j++) {
        unsigned long long key = a[j];
        int i = j - 1;
        while (i >= 0 && a[i] > key) { a[i + 1] = a[i]; i--; }
        a[i + 1] = key;
      }
      u = 1;
      for (int j = 1; j < n; j++) u += ((a[j] >> 44) != (a[j - 1] >> 44)) ? 1 : 0;
    }
  } else {
    // correctness fallback: sort in global memory
    if (n > 0) {
      unsigned long long* a = edges + off;
      for (int j = 1; j < n; j++) {
        unsigned long long key = a[j];
        int i = j - 1;
        while (i >= 0 && a[i] > key) { a[i + 1] = a[i]; i--; }
        a[i + 1] = key;
      }
      u = 1;
      for (int j = 1; j < n; j++) u += ((a[j] >> 44) != (a[j - 1] >> 44)) ? 1 : 0;
    }
  }
  int uExcl = blkExclI32(u, shScan);
  int Utot = shScan[SB - 1];
  if (threadIdx.x == 0) {
    atomicExch(&lbState[bid], (1ull << 62) | (unsigned long long)(unsigned)Utot);
    unsigned long long excl = 0;
    for (int j = bid - 1; j >= 0;) {
      unsigned long long s2 = atomicAdd(&lbState[j], 0ull);
      unsigned long long tag = s2 >> 62;
      if (tag == 0) continue;                       // predecessor not published yet
      excl += (s2 & 0xffffffffull);
      if (tag == 2) break;                          // full prefix: done
      j--;
    }
    atomicExch(&lbState[bid], (2ull << 62) | ((excl + (unsigned long long)(unsigned)Utot) & 0xffffffffull));
    shBase = (int)excl;
    if (bid == nblocks - 1) scal[3] = (int)excl + Utot;   // total E
  }
  __syncthreads();
  int r0 = shBase + uExcl;          // uniqueOff[v]
  if (n > 0) {
    int r = r0 - 1;
    unsigned long long prevHi = ~0ull;
    float s0 = sdf[v];
    float p0x = pos[3 * v], p0y = pos[3 * v + 1], p0z = pos[3 * v + 2];
    const unsigned long long* a = inLds ? (sh + (off - start)) : (edges + off);
    int lbase = off - start;
    for (int j = 0; j < n; j++) {
      unsigned long long key = a[j];
      unsigned long long hi44 = key >> 44;
      if (hi44 != prevHi) {
        prevHi = hi44;
        r++;
        int hi = (int)hi44;
        float s1 = sdf[hi];
        float ns1 = -s1;
        float denom = s0 + ns1;          // matches reference s.sum(1)
        float w0 = ns1 / denom;
        float w1 = s0 / denom;
        out[3 * r + 0] = p0x * w0 + pos[3 * hi + 0] * w1;
        out[3 * r + 1] = p0y * w0 + pos[3 * hi + 1] * w1;
        out[3 * r + 2] = p0z * w0 + pos[3 * hi + 2] * w1;
      }
      int orig = (int)(key & 0xffffull);
      if (inLds) shRank[lbase + orig] = r;
      else rankArr[off + orig] = r;
    }
  }
  __syncthreads();
  if (inLds) {
    for (int i = threadIdx.x; i < cnt; i += SB) rankArr[start + i] = shRank[i];
  }
}

// ---------------- output offsets -------------------------------------------
// scal: 0=M1 1=M2 2=totSlots 3=E 4=facesOff 5=uvsOff 6=uvidxOff
__global__ void k_offsets(int* scal, int uvsElems) {
  int M1 = scal[0], M2 = scal[1], E = scal[3];
  int F = M1 + 2 * M2;
  scal[4] = 3 * E;
  scal[5] = 3 * E + 3 * F;
  scal[6] = scal[5] + uvsElems;
}

// ---------------- faces + uv_idx (dense writes, L3-resident rank gathers) ----
__global__ void k_face(const int4* __restrict__ tet, const uint8_t* __restrict__ tetidx,
                       const unsigned long long* __restrict__ tetRank, const int* __restrict__ scal,
                       const int* __restrict__ bucketOff, const ushort4* __restrict__ stash,
                       const int* __restrict__ rankArr, float* __restrict__ out, int nt) {
  int t = blockIdx.x * blockDim.x + threadIdx.x;
  if (t >= nt) return;
  int bits = tetidx[t];
  int nt3 = c_ntri[bits];
  if (nt3 == 0) return;
  int4 v = tet[t];
  int ids[4] = {v.x, v.y, v.z, v.w};
  ushort4 stv = stash[t];
  unsigned short sta[4] = {stv.x, stv.y, stv.z, stv.w};
  int rk[6];
  int c = 0;
#pragma unroll
  for (int e = 0; e < 6; e++) {
    int a = c_ea[e], b = c_eb[e];
    if ((((bits >> a) ^ (bits >> b)) & 1) == 0) continue;
    int va = ids[a], vb = ids[b];
    int lo = va < vb ? va : vb;
    rk[e] = rankArr[bucketOff[lo] + sta[c++]];
  }
  unsigned long long pk = tetRank[t];
  int M1 = scal[0], facesOff = scal[4], uvidxOff = scal[6];
  int row = (nt3 == 1) ? (int)(pk & 0xffffffffull) : M1 + 2 * (int)(pk >> 32);
  float* f = out + facesOff + (size_t)3 * row;
  int npos = 3 * nt3;
  for (int p = 0; p < npos; p++) f[p] = (float)rk[c_tri[bits][p]];
  float* o = out + uvidxOff + (size_t)3 * row;
  float bt4 = (float)(4 * t);
  o[0] = bt4; o[1] = bt4 + 1.0f; o[2] = bt4 + 2.0f;
  if (nt3 == 2) { o[3] = bt4; o[4] = bt4 + 2.0f; o[5] = bt4 + 3.0f; }
}

// ---------------- uvs --------------------------------------------------------
__global__ void k_uvs(const int* __restrict__ scal, float* __restrict__ out, int N) {
  int i = blockIdx.x * blockDim.x + threadIdx.x;
  int total = N * N;
  if (i >= total) return;
  int ty = i / N, tx = i - ty * N;
  float x = (float)tx / (float)N;
  float y = (float)ty / (float)N;
  float pad = (float)(0.9 / (double)N);
  float* o = out + scal[5] + (size_t)i * 8;
  o[0] = x;       o[1] = y;
  o[2] = x + pad; o[3] = y;
  o[4] = x + pad; o[5] = y + pad;
  o[6] = x;       o[7] = y + pad;
}

extern "C" void kernel_launch(void* const* d_in, const int* in_sizes, int n_in,
                              void* d_out, int out_size, void* d_ws, size_t ws_size,
                              hipStream_t stream) {
  const float* pos = (const float*)d_in[0];
  const float* sdf = (const float*)d_in[1];
  const int* tet = (const int*)d_in[2];
  int nv = in_sizes[1];
  int nt = in_sizes[2] / 4;

  // workspace layout (256B aligned slices)
  char* w = (char*)d_ws;
  size_t off = 0;
  auto A = [&](size_t bytes) -> char* {
    off = (off + 255) & ~(size_t)255;
    char* p = w + off;
    off += bytes;
    return p;
  };
  int* scal = (int*)A(64 * sizeof(int));
  uint8_t* tetidx = (uint8_t*)A((size_t)nt);
  unsigned long long* tetRank = (unsigned long long*)A((size_t)nt * 8);
  int* bucketCnt = (int*)A((size_t)nv * 4);
  int* bucketOff = (int*)A((size_t)nv * 4);
  ushort4* stash = (ushort4*)A((size_t)nt * 8);
  int* rankArr = (int*)A((size_t)nt * 4 * 4);      // one int per possible occurrence
  unsigned long long* blockTotU = (unsigned long long*)A(8 * 4096);
  int* blockTotI = (int*)A(4 * 4096);
  int nbv_sort = (nv + SB - 1) / SB;
  unsigned long long* lbState = (unsigned long long*)A((size_t)nbv_sort * 8);
  int* ticket = (int*)A(256);
  unsigned long long* edges = (unsigned long long*)A((size_t)nt * 4 * 8); // <=4 crossing edges/tet

  hipMemsetAsync(bucketCnt, 0, (size_t)nv * 4, stream);
  hipMemsetAsync(lbState, 0, (size_t)nbv_sort * 8, stream);
  hipMemsetAsync(ticket, 0, 256, stream);

  int nb_t = (nt + SCHUNK - 1) / SCHUNK;
  int nb_v = (nv + SCHUNK - 1) / SCHUNK;

  k_classify<<<(nt + 255) / 256, 256, 0, stream>>>((const int4*)tet, sdf, tetidx, bucketCnt,
                                                   stash, nt);

  k_tetscan1<<<nb_t, SB, 0, stream>>>(tetidx, blockTotU, nt);
  k_scanblk_u64<<<1, SB, 0, stream>>>(blockTotU, nb_t, scal, 0, 1);
  k_tetscan3<<<nb_t, SB, 0, stream>>>(tetidx, blockTotU, tetRank, nt);

  k_i32scan1<<<nb_v, SB, 0, stream>>>(bucketCnt, blockTotI, nv);
  k_scanblk_i32<<<1, SB, 0, stream>>>(blockTotI, nb_v, scal, 2);
  k_i32scan3<<<nb_v, SB, 0, stream>>>(bucketCnt, blockTotI, bucketOff, nv);

  k_scatter<<<(nt + 255) / 256, 256, 0, stream>>>((const int4*)tet, tetidx, tetRank, scal,
                                                  bucketOff, stash, edges, nt);

  k_sortemit<<<nbv_sort, SB, 0, stream>>>(bucketOff, bucketCnt, edges, pos, sdf,
                                          rankArr, (float*)d_out, scal, lbState, ticket,
                                          nv, nbv_sort);

  long long maxidx = (long long)nt * 2;
  int N = (int)ceil(sqrt((double)((maxidx + 1) / 2)));
  int uvsElems = N * N * 8;

  k_offsets<<<1, 1, 0, stream>>>(scal, uvsElems);
  k_face<<<(nt + 255) / 256, 256, 0, stream>>>((const int4*)tet, tetidx, tetRank, scal,
                                               bucketOff, stash, rankArr, (float*)d_out, nt);
  k_uvs<<<(N * N + 255) / 256, 256, 0, stream>>>(scal, (float*)d_out, N);
}

// Round 6
// 1117.044 us; speedup vs baseline: 1.0518x; 1.0518x over previous
//
#include <hip/hip_runtime.h>
#include <stdint.h>
#include <math.h>

#define SB 256
#define SI 8
#define SCHUNK (SB*SI)
#define SORT_LDS 4096   // u64 entries = 32 KB sort buf; mean block need ~3072

__constant__ int c_tri[16][6] = {
  {-1,-1,-1,-1,-1,-1},{1,0,2,-1,-1,-1},{4,0,3,-1,-1,-1},{1,4,2,1,3,4},
  {3,1,5,-1,-1,-1},{2,3,0,2,5,3},{1,4,0,1,5,4},{4,2,5,-1,-1,-1},
  {4,5,2,-1,-1,-1},{4,1,0,4,5,1},{3,2,0,3,5,2},{1,3,5,-1,-1,-1},
  {4,1,2,4,3,1},{3,0,4,-1,-1,-1},{2,0,1,-1,-1,-1},{-1,-1,-1,-1,-1,-1}};
__constant__ int c_ntri[16] = {0,1,1,2,1,2,2,1,1,2,2,1,2,1,1,0};
__constant__ int c_ea[6] = {0,0,0,1,1,2};
__constant__ int c_eb[6] = {1,2,3,2,3,3};

// ---------------- classify tets: occupancy bits + bucket count + slot stash --
__global__ void k_classify(const int4* __restrict__ tet, const float* __restrict__ sdf,
                           uint8_t* __restrict__ tetidx, int* __restrict__ bucketCnt,
                           ushort4* __restrict__ stash, int nt) {
  int t = blockIdx.x * blockDim.x + threadIdx.x;
  if (t >= nt) return;
  int4 v = tet[t];
  int ids[4] = {v.x, v.y, v.z, v.w};
  int bits = 0;
#pragma unroll
  for (int i = 0; i < 4; i++) bits |= (sdf[ids[i]] > 0.0f) ? (1 << i) : 0;
  tetidx[t] = (uint8_t)bits;
  if (c_ntri[bits] == 0) return;
  unsigned short st[4] = {0, 0, 0, 0};
  int c = 0;
#pragma unroll
  for (int e = 0; e < 6; e++) {
    int a = c_ea[e], b = c_eb[e];
    if ((((bits >> a) ^ (bits >> b)) & 1) == 0) continue;
    int va = ids[a], vb = ids[b];
    int lo = va < vb ? va : vb;
    st[c++] = (unsigned short)atomicAdd(&bucketCnt[lo], 1);
  }
  stash[t] = make_ushort4(st[0], st[1], st[2], st[3]);
}

// ---------------- block exclusive scans -------------------------------------
__device__ inline unsigned long long blkExclU64(unsigned long long val, unsigned long long* sh) {
  int tid = threadIdx.x;
  sh[tid] = val; __syncthreads();
  for (int st = 1; st < SB; st <<= 1) {
    unsigned long long add = (tid >= st) ? sh[tid - st] : 0ull;
    __syncthreads();
    sh[tid] += add;
    __syncthreads();
  }
  return sh[tid] - val;
}
__device__ inline int blkExclI32(int val, int* sh) {
  int tid = threadIdx.x;
  sh[tid] = val; __syncthreads();
  for (int st = 1; st < SB; st <<= 1) {
    int add = (tid >= st) ? sh[tid - st] : 0;
    __syncthreads();
    sh[tid] += add;
    __syncthreads();
  }
  return sh[tid] - val;
}

// tet scan: value = (ntri==1) | (ntri==2)<<32
__global__ void k_tetscan1(const uint8_t* __restrict__ tetidx, unsigned long long* __restrict__ bt, int n) {
  __shared__ unsigned long long sh[SB];
  int base = blockIdx.x * SCHUNK + threadIdx.x * SI;
  unsigned long long s = 0;
  for (int k = 0; k < SI; k++) {
    int i = base + k;
    if (i < n) {
      int nt3 = c_ntri[tetidx[i]];
      s += (nt3 == 1 ? 1ull : 0ull) + (nt3 == 2 ? (1ull << 32) : 0ull);
    }
  }
  sh[threadIdx.x] = s; __syncthreads();
  for (int st = SB / 2; st > 0; st >>= 1) {
    if (threadIdx.x < st) sh[threadIdx.x] += sh[threadIdx.x + st];
    __syncthreads();
  }
  if (threadIdx.x == 0) bt[blockIdx.x] = sh[0];
}

__global__ void k_scanblk_u64(unsigned long long* __restrict__ bt, int nb,
                              int* __restrict__ scal, int slotLo, int slotHi) {
  __shared__ unsigned long long sh[SB];
  __shared__ unsigned long long carrySh;
  if (threadIdx.x == 0) carrySh = 0;
  __syncthreads();
  for (int base = 0; base < nb; base += SB) {
    int i = base + threadIdx.x;
    unsigned long long v = (i < nb) ? bt[i] : 0ull;
    unsigned long long ex = blkExclU64(v, sh);
    unsigned long long carry = carrySh;
    if (i < nb) bt[i] = carry + ex;
    __syncthreads();
    if (threadIdx.x == SB - 1) carrySh = carry + ex + v;
    __syncthreads();
  }
  if (threadIdx.x == 0) {
    scal[slotLo] = (int)(carrySh & 0xffffffffull);
    scal[slotHi] = (int)(carrySh >> 32);
  }
}

__global__ void k_tetscan3(const uint8_t* __restrict__ tetidx, const unsigned long long* __restrict__ bt,
                           unsigned long long* __restrict__ tetRank, int n) {
  __shared__ unsigned long long sh[SB];
  int base = blockIdx.x * SCHUNK + threadIdx.x * SI;
  unsigned long long vals[SI];
  unsigned long long s = 0;
  for (int k = 0; k < SI; k++) {
    int i = base + k;
    unsigned long long v = 0;
    if (i < n) {
      int nt3 = c_ntri[tetidx[i]];
      v = (nt3 == 1 ? 1ull : 0ull) + (nt3 == 2 ? (1ull << 32) : 0ull);
    }
    vals[k] = s; s += v;
  }
  unsigned long long thrOff = blkExclU64(s, sh);
  unsigned long long off = bt[blockIdx.x] + thrOff;
  for (int k = 0; k < SI; k++) {
    int i = base + k;
    if (i < n) tetRank[i] = off + vals[k];
  }
}

__global__ void k_i32scan1(const int* __restrict__ src, int* __restrict__ bt, int n) {
  __shared__ int sh[SB];
  int base = blockIdx.x * SCHUNK + threadIdx.x * SI;
  int s = 0;
  for (int k = 0; k < SI; k++) { int i = base + k; if (i < n) s += src[i]; }
  sh[threadIdx.x] = s; __syncthreads();
  for (int st = SB / 2; st > 0; st >>= 1) {
    if (threadIdx.x < st) sh[threadIdx.x] += sh[threadIdx.x + st];
    __syncthreads();
  }
  if (threadIdx.x == 0) bt[blockIdx.x] = sh[0];
}

__global__ void k_scanblk_i32(int* __restrict__ bt, int nb, int* __restrict__ scal, int slot) {
  __shared__ int sh[SB];
  __shared__ int carrySh;
  if (threadIdx.x == 0) carrySh = 0;
  __syncthreads();
  for (int base = 0; base < nb; base += SB) {
    int i = base + threadIdx.x;
    int v = (i < nb) ? bt[i] : 0;
    int ex = blkExclI32(v, sh);
    int carry = carrySh;
    if (i < nb) bt[i] = carry + ex;
    __syncthreads();
    if (threadIdx.x == SB - 1) carrySh = carry + ex + v;
    __syncthreads();
  }
  if (threadIdx.x == 0) scal[slot] = carrySh;
}

// scan pass 3; optionally zips pairOff[i] = {bucketOff[i], scanVal}
__global__ void k_i32scan3(const int* __restrict__ src, const int* __restrict__ bt,
                           int* __restrict__ dst, const int* __restrict__ bOff,
                           int2* __restrict__ pairOff, int n) {
  __shared__ int sh[SB];
  int base = blockIdx.x * SCHUNK + threadIdx.x * SI;
  int vals[SI];
  int s = 0;
  for (int k = 0; k < SI; k++) {
    int i = base + k;
    int v = (i < n) ? src[i] : 0;
    vals[k] = s; s += v;
  }
  int thrOff = blkExclI32(s, sh);
  int off = bt[blockIdx.x] + thrOff;
  for (int k = 0; k < SI; k++) {
    int i = base + k;
    if (i < n) {
      int val = off + vals[k];
      dst[i] = val;
      if (pairOff) pairOff[i] = make_int2(bOff[i], val);
    }
  }
}

// ---------------- scatter (atomic-free) --------------------------------------
// key: [63:44]=hi [43:20]=pos1 (face elem idx) [19:17]=delta [16]=has2 [15:0]=origIdxInBucket
__global__ void k_scatter(const int4* __restrict__ tet, const uint8_t* __restrict__ tetidx,
                          const unsigned long long* __restrict__ tetRank, const int* __restrict__ scal,
                          const int* __restrict__ bucketOff, const ushort4* __restrict__ stash,
                          unsigned long long* __restrict__ edges, int nt) {
  int t = blockIdx.x * blockDim.x + threadIdx.x;
  if (t >= nt) return;
  int bits = tetidx[t];
  int nt3 = c_ntri[bits];
  if (nt3 == 0) return;
  int4 v = tet[t];
  int ids[4] = {v.x, v.y, v.z, v.w};
  unsigned long long pk = tetRank[t];
  int M1 = scal[0];
  int rowElemBase = (nt3 == 1) ? 3 * (int)(pk & 0xffffffffull)
                               : 3 * M1 + 6 * (int)(pk >> 32);
  ushort4 stv = stash[t];
  unsigned short sta[4] = {stv.x, stv.y, stv.z, stv.w};
  int npos = 3 * nt3;
  int c = 0;
#pragma unroll
  for (int e = 0; e < 6; e++) {
    int a = c_ea[e], b = c_eb[e];
    if ((((bits >> a) ^ (bits >> b)) & 1) == 0) continue;
    int va = ids[a], vb = ids[b];
    int lo = va < vb ? va : vb;
    int hi = va < vb ? vb : va;
    int p1 = -1, p2 = -1;
    for (int p = 0; p < npos; p++) {
      if (c_tri[bits][p] == e) { if (p1 < 0) p1 = p; else p2 = p; }
    }
    int orig = sta[c++];
    unsigned long long key = ((unsigned long long)(unsigned)hi << 44)
                           | ((unsigned long long)(unsigned)(rowElemBase + p1) << 20)
                           | ((p2 >= 0) ? (((unsigned long long)(p2 - p1) << 17) | (1ull << 16)) : 0ull)
                           | (unsigned long long)orig;
    edges[bucketOff[lo] + orig] = key;
  }
}

// ---------------- sort buckets + local head ranks + in-place unique compact --
// Per bucket v (one thread): sort entries in LDS; for each occurrence, write
// its bucket-local unique index (hrank, u16) in ORIGINAL order; compact unique
// (lo<<32|hi) pairs in place over the sorted keys (write idx u-1 <= read idx j,
// always safe). Dumps hrank + compacted edges coalesced. uniqueCnt[v]=u.
__global__ __launch_bounds__(SB) void k_sortuniq(
    const int* __restrict__ bucketOff, const int* __restrict__ bucketCnt,
    unsigned long long* __restrict__ edges, unsigned short* __restrict__ hrankArr,
    int* __restrict__ uniqueCnt, int nv) {
  __shared__ unsigned long long sh[SORT_LDS];
  __shared__ unsigned short shR[SORT_LDS];
  int v0 = blockIdx.x * SB;
  int vLast = v0 + SB - 1;
  if (vLast >= nv) vLast = nv - 1;
  int start = bucketOff[v0];
  int end = bucketOff[vLast] + bucketCnt[vLast];
  int cnt = end - start;
  int v = v0 + threadIdx.x;
  int n = (v < nv) ? bucketCnt[v] : 0;
  int off = (v < nv) ? bucketOff[v] : start;
  if (cnt <= SORT_LDS) {
    for (int i = threadIdx.x; i < cnt; i += SB) sh[i] = edges[start + i];
    __syncthreads();
    if (v < nv) {
      if (n == 0) { uniqueCnt[v] = 0; }
      else {
        int lbase = off - start;
        unsigned long long* a = sh + lbase;
        for (int j = 1; j < n; j++) {
          unsigned long long key = a[j];
          int i = j - 1;
          while (i >= 0 && a[i] > key) { a[i + 1] = a[i]; i--; }
          a[i + 1] = key;
        }
        int u = 0;
        unsigned long long prevHi = ~0ull;
        for (int j = 0; j < n; j++) {
          unsigned long long key = a[j];
          unsigned long long hi44 = key >> 44;
          if (hi44 != prevHi) {
            prevHi = hi44;
            a[u] = ((unsigned long long)(unsigned)v << 32) | (unsigned)(hi44);
            u++;
          }
          shR[lbase + (int)(key & 0xffffull)] = (unsigned short)(u - 1);
        }
        uniqueCnt[v] = u;
      }
    }
    __syncthreads();
    for (int i = threadIdx.x; i < cnt; i += SB) {
      edges[start + i] = sh[i];
      hrankArr[start + i] = shR[i];
    }
  } else {
    // correctness fallback: operate in global memory
    if (v < nv) {
      if (n == 0) { uniqueCnt[v] = 0; return; }
      unsigned long long* a = edges + off;
      for (int j = 1; j < n; j++) {
        unsigned long long key = a[j];
        int i = j - 1;
        while (i >= 0 && a[i] > key) { a[i + 1] = a[i]; i--; }
        a[i + 1] = key;
      }
      int u = 0;
      unsigned long long prevHi = ~0ull;
      for (int j = 0; j < n; j++) {
        unsigned long long key = a[j];
        unsigned long long hi44 = key >> 44;
        if (hi44 != prevHi) {
          prevHi = hi44;
          a[u] = ((unsigned long long)(unsigned)v << 32) | (unsigned)(hi44);
          u++;
        }
        hrankArr[off + (int)(key & 0xffffull)] = (unsigned short)(u - 1);
      }
      uniqueCnt[v] = u;
    }
  }
}

// ---------------- output offsets -------------------------------------------
// scal: 0=M1 1=M2 2=totSlots 3=E 4=facesOff 5=uvsOff 6=uvidxOff
__global__ void k_offsets(int* scal, int uvsElems) {
  int M1 = scal[0], M2 = scal[1], E = scal[3];
  int F = M1 + 2 * M2;
  scal[4] = 3 * E;
  scal[5] = 3 * E + 3 * F;
  scal[6] = scal[5] + uvsElems;
}

// ---------------- verts: LDS compact then one-thread-per-vertex emit ---------
__global__ __launch_bounds__(SB) void k_verts(
    const int* __restrict__ bucketOff, const int* __restrict__ bucketCnt,
    const int* __restrict__ uniqueOff, const int* __restrict__ uniqueCnt,
    const unsigned long long* __restrict__ edges,
    const float* __restrict__ pos, const float* __restrict__ sdf,
    float* __restrict__ out, int nv) {
  __shared__ unsigned long long shOut[SORT_LDS];
  int v0 = blockIdx.x * SB;
  int vLast = v0 + SB - 1;
  if (vLast >= nv) vLast = nv - 1;
  int Ustart = uniqueOff[v0];
  int Utot = uniqueOff[vLast] + uniqueCnt[vLast] - Ustart;
  int v = v0 + threadIdx.x;
  int u = (v < nv) ? uniqueCnt[v] : 0;
  int boff = (v < nv) ? bucketOff[v] : 0;
  int lofs = (v < nv) ? (uniqueOff[v] - Ustart) : 0;
  if (Utot <= SORT_LDS) {
    for (int k = 0; k < u; k++) shOut[lofs + k] = edges[boff + k];
    __syncthreads();
    for (int i = threadIdx.x; i < Utot; i += SB) {
      unsigned long long q = shOut[i];
      int lo = (int)(q >> 32);
      int hi = (int)(q & 0xffffffffull);
      float s0 = sdf[lo];
      float ns1 = -sdf[hi];
      float denom = s0 + ns1;          // matches reference s.sum(1)
      float w0 = ns1 / denom;
      float w1 = s0 / denom;
      int r = Ustart + i;
      out[3 * r + 0] = pos[3 * lo + 0] * w0 + pos[3 * hi + 0] * w1;
      out[3 * r + 1] = pos[3 * lo + 1] * w0 + pos[3 * hi + 1] * w1;
      out[3 * r + 2] = pos[3 * lo + 2] * w0 + pos[3 * hi + 2] * w1;
    }
  } else {
    // correctness fallback: direct per-bucket emit
    for (int k = 0; k < u; k++) {
      unsigned long long q = edges[boff + k];
      int lo = (int)(q >> 32);
      int hi = (int)(q & 0xffffffffull);
      float s0 = sdf[lo];
      float ns1 = -sdf[hi];
      float denom = s0 + ns1;
      float w0 = ns1 / denom;
      float w1 = s0 / denom;
      int r = Ustart + lofs + k;
      out[3 * r + 0] = pos[3 * lo + 0] * w0 + pos[3 * hi + 0] * w1;
      out[3 * r + 1] = pos[3 * lo + 1] * w0 + pos[3 * hi + 1] * w1;
      out[3 * r + 2] = pos[3 * lo + 2] * w0 + pos[3 * hi + 2] * w1;
    }
  }
}

// ---------------- faces + uv_idx (dense writes; pairOff+hrank gathers) -------
__global__ void k_face(const int4* __restrict__ tet, const uint8_t* __restrict__ tetidx,
                       const unsigned long long* __restrict__ tetRank, const int* __restrict__ scal,
                       const int2* __restrict__ pairOff, const ushort4* __restrict__ stash,
                       const unsigned short* __restrict__ hrankArr, float* __restrict__ out, int nt) {
  int t = blockIdx.x * blockDim.x + threadIdx.x;
  if (t >= nt) return;
  int bits = tetidx[t];
  int nt3 = c_ntri[bits];
  if (nt3 == 0) return;
  int4 v = tet[t];
  int ids[4] = {v.x, v.y, v.z, v.w};
  ushort4 stv = stash[t];
  unsigned short sta[4] = {stv.x, stv.y, stv.z, stv.w};
  int rk[6];
  int c = 0;
#pragma unroll
  for (int e = 0; e < 6; e++) {
    int a = c_ea[e], b = c_eb[e];
    if ((((bits >> a) ^ (bits >> b)) & 1) == 0) continue;
    int va = ids[a], vb = ids[b];
    int lo = va < vb ? va : vb;
    int2 po = pairOff[lo];
    rk[e] = po.y + (int)hrankArr[po.x + sta[c++]];
  }
  unsigned long long pk = tetRank[t];
  int M1 = scal[0], facesOff = scal[4], uvidxOff = scal[6];
  int row = (nt3 == 1) ? (int)(pk & 0xffffffffull) : M1 + 2 * (int)(pk >> 32);
  float* f = out + facesOff + (size_t)3 * row;
  int npos = 3 * nt3;
  for (int p = 0; p < npos; p++) f[p] = (float)rk[c_tri[bits][p]];
  float* o = out + uvidxOff + (size_t)3 * row;
  float bt4 = (float)(4 * t);
  o[0] = bt4; o[1] = bt4 + 1.0f; o[2] = bt4 + 2.0f;
  if (nt3 == 2) { o[3] = bt4; o[4] = bt4 + 2.0f; o[5] = bt4 + 3.0f; }
}

// ---------------- uvs --------------------------------------------------------
__global__ void k_uvs(const int* __restrict__ scal, float* __restrict__ out, int N) {
  int i = blockIdx.x * blockDim.x + threadIdx.x;
  int total = N * N;
  if (i >= total) return;
  int ty = i / N, tx = i - ty * N;
  float x = (float)tx / (float)N;
  float y = (float)ty / (float)N;
  float pad = (float)(0.9 / (double)N);
  float* o = out + scal[5] + (size_t)i * 8;
  o[0] = x;       o[1] = y;
  o[2] = x + pad; o[3] = y;
  o[4] = x + pad; o[5] = y + pad;
  o[6] = x;       o[7] = y + pad;
}

extern "C" void kernel_launch(void* const* d_in, const int* in_sizes, int n_in,
                              void* d_out, int out_size, void* d_ws, size_t ws_size,
                              hipStream_t stream) {
  const float* pos = (const float*)d_in[0];
  const float* sdf = (const float*)d_in[1];
  const int* tet = (const int*)d_in[2];
  int nv = in_sizes[1];
  int nt = in_sizes[2] / 4;

  // workspace layout (256B aligned slices)
  char* w = (char*)d_ws;
  size_t off = 0;
  auto A = [&](size_t bytes) -> char* {
    off = (off + 255) & ~(size_t)255;
    char* p = w + off;
    off += bytes;
    return p;
  };
  int* scal = (int*)A(64 * sizeof(int));
  uint8_t* tetidx = (uint8_t*)A((size_t)nt);
  unsigned long long* tetRank = (unsigned long long*)A((size_t)nt * 8);
  int* bucketCnt = (int*)A((size_t)nv * 4);
  int* bucketOff = (int*)A((size_t)nv * 4);
  int* uniqueCnt = (int*)A((size_t)nv * 4);
  int* uniqueOff = (int*)A((size_t)nv * 4);
  int2* pairOff = (int2*)A((size_t)nv * 8);
  ushort4* stash = (ushort4*)A((size_t)nt * 8);
  unsigned short* hrankArr = (unsigned short*)A((size_t)nt * 4 * 2);
  unsigned long long* blockTotU = (unsigned long long*)A(8 * 4096);
  int* blockTotI = (int*)A(4 * 4096);
  unsigned long long* edges = (unsigned long long*)A((size_t)nt * 4 * 8); // <=4 crossing edges/tet

  hipMemsetAsync(bucketCnt, 0, (size_t)nv * 4, stream);

  int nb_t = (nt + SCHUNK - 1) / SCHUNK;
  int nb_v = (nv + SCHUNK - 1) / SCHUNK;
  int nbv_sort = (nv + SB - 1) / SB;

  k_classify<<<(nt + 255) / 256, 256, 0, stream>>>((const int4*)tet, sdf, tetidx, bucketCnt,
                                                   stash, nt);

  k_tetscan1<<<nb_t, SB, 0, stream>>>(tetidx, blockTotU, nt);
  k_scanblk_u64<<<1, SB, 0, stream>>>(blockTotU, nb_t, scal, 0, 1);
  k_tetscan3<<<nb_t, SB, 0, stream>>>(tetidx, blockTotU, tetRank, nt);

  k_i32scan1<<<nb_v, SB, 0, stream>>>(bucketCnt, blockTotI, nv);
  k_scanblk_i32<<<1, SB, 0, stream>>>(blockTotI, nb_v, scal, 2);
  k_i32scan3<<<nb_v, SB, 0, stream>>>(bucketCnt, blockTotI, bucketOff,
                                      (const int*)nullptr, (int2*)nullptr, nv);

  k_scatter<<<(nt + 255) / 256, 256, 0, stream>>>((const int4*)tet, tetidx, tetRank, scal,
                                                  bucketOff, stash, edges, nt);

  k_sortuniq<<<nbv_sort, SB, 0, stream>>>(bucketOff, bucketCnt, edges, hrankArr,
                                          uniqueCnt, nv);

  k_i32scan1<<<nb_v, SB, 0, stream>>>(uniqueCnt, blockTotI, nv);
  k_scanblk_i32<<<1, SB, 0, stream>>>(blockTotI, nb_v, scal, 3);
  k_i32scan3<<<nb_v, SB, 0, stream>>>(uniqueCnt, blockTotI, uniqueOff,
                                      bucketOff, pairOff, nv);

  long long maxidx = (long long)nt * 2;
  int N = (int)ceil(sqrt((double)((maxidx + 1) / 2)));
  int uvsElems = N * N * 8;

  k_offsets<<<1, 1, 0, stream>>>(scal, uvsElems);
  k_verts<<<nbv_sort, SB, 0, stream>>>(bucketOff, bucketCnt, uniqueOff, uniqueCnt,
                                       edges, pos, sdf, (float*)d_out, nv);
  k_face<<<(nt + 255) / 256, 256, 0, stream>>>((const int4*)tet, tetidx, tetRank, scal,
                                               pairOff, stash, hrankArr, (float*)d_out, nt);
  k_uvs<<<(N * N + 255) / 256, 256, 0, stream>>>(scal, (float*)d_out, N);
}

// Round 7
// 981.890 us; speedup vs baseline: 1.1966x; 1.1376x over previous
//
#include <hip/hip_runtime.h>
#include <stdint.h>
#include <math.h>

#define SB 256
#define SI 8
#define SCHUNK (SB*SI)
#define SORT_LDS 4096   // entries per 256-bucket block; mean need ~3114
#define ORIG_BITS 13
#define ORIG_MASK 0x1fffu

__constant__ int c_tri[16][6] = {
  {-1,-1,-1,-1,-1,-1},{1,0,2,-1,-1,-1},{4,0,3,-1,-1,-1},{1,4,2,1,3,4},
  {3,1,5,-1,-1,-1},{2,3,0,2,5,3},{1,4,0,1,5,4},{4,2,5,-1,-1,-1},
  {4,5,2,-1,-1,-1},{4,1,0,4,5,1},{3,2,0,3,5,2},{1,3,5,-1,-1,-1},
  {4,1,2,4,3,1},{3,0,4,-1,-1,-1},{2,0,1,-1,-1,-1},{-1,-1,-1,-1,-1,-1}};
__constant__ int c_ntri[16] = {0,1,1,2,1,2,2,1,1,2,2,1,2,1,1,0};
__constant__ int c_ea[6] = {0,0,0,1,1,2};
__constant__ int c_eb[6] = {1,2,3,2,3,3};

// ---------------- classify tets: occupancy bits + bucket count + slot stash --
__global__ void k_classify(const int4* __restrict__ tet, const float* __restrict__ sdf,
                           uint8_t* __restrict__ tetidx, int* __restrict__ bucketCnt,
                           ushort4* __restrict__ stash, int nt) {
  int t = blockIdx.x * blockDim.x + threadIdx.x;
  if (t >= nt) return;
  int4 v = tet[t];
  int ids[4] = {v.x, v.y, v.z, v.w};
  int bits = 0;
#pragma unroll
  for (int i = 0; i < 4; i++) bits |= (sdf[ids[i]] > 0.0f) ? (1 << i) : 0;
  tetidx[t] = (uint8_t)bits;
  if (c_ntri[bits] == 0) return;
  unsigned short st[4] = {0, 0, 0, 0};
  int c = 0;
#pragma unroll
  for (int e = 0; e < 6; e++) {
    int a = c_ea[e], b = c_eb[e];
    if ((((bits >> a) ^ (bits >> b)) & 1) == 0) continue;
    int va = ids[a], vb = ids[b];
    int lo = va < vb ? va : vb;
    st[c++] = (unsigned short)atomicAdd(&bucketCnt[lo], 1);
  }
  stash[t] = make_ushort4(st[0], st[1], st[2], st[3]);
}

// ---------------- block exclusive scans -------------------------------------
__device__ inline unsigned long long blkExclU64(unsigned long long val, unsigned long long* sh) {
  int tid = threadIdx.x;
  sh[tid] = val; __syncthreads();
  for (int st = 1; st < SB; st <<= 1) {
    unsigned long long add = (tid >= st) ? sh[tid - st] : 0ull;
    __syncthreads();
    sh[tid] += add;
    __syncthreads();
  }
  return sh[tid] - val;
}
__device__ inline int blkExclI32(int val, int* sh) {
  int tid = threadIdx.x;
  sh[tid] = val; __syncthreads();
  for (int st = 1; st < SB; st <<= 1) {
    int add = (tid >= st) ? sh[tid - st] : 0;
    __syncthreads();
    sh[tid] += add;
    __syncthreads();
  }
  return sh[tid] - val;
}

// tet scan: value = (ntri==1) | (ntri==2)<<32
__global__ void k_tetscan1(const uint8_t* __restrict__ tetidx, unsigned long long* __restrict__ bt, int n) {
  __shared__ unsigned long long sh[SB];
  int base = blockIdx.x * SCHUNK + threadIdx.x * SI;
  unsigned long long s = 0;
  for (int k = 0; k < SI; k++) {
    int i = base + k;
    if (i < n) {
      int nt3 = c_ntri[tetidx[i]];
      s += (nt3 == 1 ? 1ull : 0ull) + (nt3 == 2 ? (1ull << 32) : 0ull);
    }
  }
  sh[threadIdx.x] = s; __syncthreads();
  for (int st = SB / 2; st > 0; st >>= 1) {
    if (threadIdx.x < st) sh[threadIdx.x] += sh[threadIdx.x + st];
    __syncthreads();
  }
  if (threadIdx.x == 0) bt[blockIdx.x] = sh[0];
}

__global__ void k_scanblk_u64(unsigned long long* __restrict__ bt, int nb,
                              int* __restrict__ scal, int slotLo, int slotHi) {
  __shared__ unsigned long long sh[SB];
  __shared__ unsigned long long carrySh;
  if (threadIdx.x == 0) carrySh = 0;
  __syncthreads();
  for (int base = 0; base < nb; base += SB) {
    int i = base + threadIdx.x;
    unsigned long long v = (i < nb) ? bt[i] : 0ull;
    unsigned long long ex = blkExclU64(v, sh);
    unsigned long long carry = carrySh;
    if (i < nb) bt[i] = carry + ex;
    __syncthreads();
    if (threadIdx.x == SB - 1) carrySh = carry + ex + v;
    __syncthreads();
  }
  if (threadIdx.x == 0) {
    scal[slotLo] = (int)(carrySh & 0xffffffffull);
    scal[slotHi] = (int)(carrySh >> 32);
  }
}

__global__ void k_tetscan3(const uint8_t* __restrict__ tetidx, const unsigned long long* __restrict__ bt,
                           unsigned long long* __restrict__ tetRank, int n) {
  __shared__ unsigned long long sh[SB];
  int base = blockIdx.x * SCHUNK + threadIdx.x * SI;
  unsigned long long vals[SI];
  unsigned long long s = 0;
  for (int k = 0; k < SI; k++) {
    int i = base + k;
    unsigned long long v = 0;
    if (i < n) {
      int nt3 = c_ntri[tetidx[i]];
      v = (nt3 == 1 ? 1ull : 0ull) + (nt3 == 2 ? (1ull << 32) : 0ull);
    }
    vals[k] = s; s += v;
  }
  unsigned long long thrOff = blkExclU64(s, sh);
  unsigned long long off = bt[blockIdx.x] + thrOff;
  for (int k = 0; k < SI; k++) {
    int i = base + k;
    if (i < n) tetRank[i] = off + vals[k];
  }
}

__global__ void k_i32scan1(const int* __restrict__ src, int* __restrict__ bt, int n) {
  __shared__ int sh[SB];
  int base = blockIdx.x * SCHUNK + threadIdx.x * SI;
  int s = 0;
  for (int k = 0; k < SI; k++) { int i = base + k; if (i < n) s += src[i]; }
  sh[threadIdx.x] = s; __syncthreads();
  for (int st = SB / 2; st > 0; st >>= 1) {
    if (threadIdx.x < st) sh[threadIdx.x] += sh[threadIdx.x + st];
    __syncthreads();
  }
  if (threadIdx.x == 0) bt[blockIdx.x] = sh[0];
}

__global__ void k_scanblk_i32(int* __restrict__ bt, int nb, int* __restrict__ scal, int slot) {
  __shared__ int sh[SB];
  __shared__ int carrySh;
  if (threadIdx.x == 0) carrySh = 0;
  __syncthreads();
  for (int base = 0; base < nb; base += SB) {
    int i = base + threadIdx.x;
    int v = (i < nb) ? bt[i] : 0;
    int ex = blkExclI32(v, sh);
    int carry = carrySh;
    if (i < nb) bt[i] = carry + ex;
    __syncthreads();
    if (threadIdx.x == SB - 1) carrySh = carry + ex + v;
    __syncthreads();
  }
  if (threadIdx.x == 0) scal[slot] = carrySh;
}

__global__ void k_i32scan3(const int* __restrict__ src, const int* __restrict__ bt,
                           int* __restrict__ dst, int n) {
  __shared__ int sh[SB];
  int base = blockIdx.x * SCHUNK + threadIdx.x * SI;
  int vals[SI];
  int s = 0;
  for (int k = 0; k < SI; k++) {
    int i = base + k;
    int v = (i < n) ? src[i] : 0;
    vals[k] = s; s += v;
  }
  int thrOff = blkExclI32(s, sh);
  int off = bt[blockIdx.x] + thrOff;
  for (int k = 0; k < SI; k++) {
    int i = base + k;
    if (i < n) dst[i] = off + vals[k];
  }
}

// ---------------- scatter: u32 keys + absolute occurrence index per tet ------
__global__ void k_scatter(const int4* __restrict__ tet, const uint8_t* __restrict__ tetidx,
                          const int* __restrict__ bucketOff, const ushort4* __restrict__ stash,
                          unsigned* __restrict__ edges32, int4* __restrict__ stashAbs, int nt) {
  int t = blockIdx.x * blockDim.x + threadIdx.x;
  if (t >= nt) return;
  int bits = tetidx[t];
  if (c_ntri[bits] == 0) return;
  int4 v = tet[t];
  int ids[4] = {v.x, v.y, v.z, v.w};
  ushort4 stv = stash[t];
  unsigned short sta[4] = {stv.x, stv.y, stv.z, stv.w};
  int sa[4] = {0, 0, 0, 0};
  int c = 0;
#pragma unroll
  for (int e = 0; e < 6; e++) {
    int a = c_ea[e], b = c_eb[e];
    if ((((bits >> a) ^ (bits >> b)) & 1) == 0) continue;
    int va = ids[a], vb = ids[b];
    int lo = va < vb ? va : vb;
    int hi = va < vb ? vb : va;
    int orig = sta[c];
    int abs = bucketOff[lo] + orig;
    edges32[abs] = ((unsigned)hi << ORIG_BITS) | (unsigned)orig;
    sa[c] = abs;
    c++;
  }
  stashAbs[t] = make_int4(sa[0], sa[1], sa[2], sa[3]);
}

// ---------------- sort buckets (u32), local head ranks, in-place hi compact --
// Per bucket v (one thread): sort (hi<<13|orig) in LDS; hrank[orig] = rank of
// this occurrence's hi among sorted distinct his (u16); compact distinct hi
// values in place into first u slots. lo is implicit (= bucket id).
__global__ __launch_bounds__(SB) void k_sortuniq(
    const int* __restrict__ bucketOff, const int* __restrict__ bucketCnt,
    unsigned* __restrict__ edges32, unsigned short* __restrict__ hrankArr,
    int* __restrict__ uniqueCnt, int nv) {
  __shared__ unsigned sh[SORT_LDS];
  __shared__ unsigned short shR[SORT_LDS];
  int v0 = blockIdx.x * SB;
  int vLast = v0 + SB - 1;
  if (vLast >= nv) vLast = nv - 1;
  int start = bucketOff[v0];
  int end = bucketOff[vLast] + bucketCnt[vLast];
  int cnt = end - start;
  int v = v0 + threadIdx.x;
  int n = (v < nv) ? bucketCnt[v] : 0;
  int off = (v < nv) ? bucketOff[v] : start;
  if (cnt <= SORT_LDS) {
    for (int i = threadIdx.x; i < cnt; i += SB) sh[i] = edges32[start + i];
    __syncthreads();
    if (v < nv) {
      if (n == 0) { uniqueCnt[v] = 0; }
      else {
        int lbase = off - start;
        unsigned* a = sh + lbase;
        for (int j = 1; j < n; j++) {
          unsigned key = a[j];
          int i = j - 1;
          while (i >= 0 && a[i] > key) { a[i + 1] = a[i]; i--; }
          a[i + 1] = key;
        }
        int u = 0;
        unsigned prevHi = 0xffffffffu;
        for (int j = 0; j < n; j++) {
          unsigned key = a[j];
          unsigned hi = key >> ORIG_BITS;
          if (hi != prevHi) { prevHi = hi; a[u] = hi; u++; }   // write idx u-1 <= j
          shR[lbase + (int)(key & ORIG_MASK)] = (unsigned short)(u - 1);
        }
        uniqueCnt[v] = u;
      }
    }
    __syncthreads();
    for (int i = threadIdx.x; i < cnt; i += SB) {
      edges32[start + i] = sh[i];
      hrankArr[start + i] = shR[i];
    }
  } else {
    // correctness fallback: operate in global memory
    if (v < nv) {
      if (n == 0) { uniqueCnt[v] = 0; return; }
      unsigned* a = edges32 + off;
      for (int j = 1; j < n; j++) {
        unsigned key = a[j];
        int i = j - 1;
        while (i >= 0 && a[i] > key) { a[i + 1] = a[i]; i--; }
        a[i + 1] = key;
      }
      int u = 0;
      unsigned prevHi = 0xffffffffu;
      for (int j = 0; j < n; j++) {
        unsigned key = a[j];
        unsigned hi = key >> ORIG_BITS;
        if (hi != prevHi) { prevHi = hi; a[u] = hi; u++; }
        hrankArr[off + (int)(key & ORIG_MASK)] = (unsigned short)(u - 1);
      }
      uniqueCnt[v] = u;
    }
  }
}

// ---------------- output offsets -------------------------------------------
// scal: 0=M1 1=M2 2=totSlots 3=E 4=facesOff 5=uvsOff 6=uvidxOff
__global__ void k_offsets(int* scal, int uvsElems) {
  int M1 = scal[0], M2 = scal[1], E = scal[3];
  int F = M1 + 2 * M2;
  scal[4] = 3 * E;
  scal[5] = 3 * E + 3 * F;
  scal[6] = scal[5] + uvsElems;
}

// ---------------- verts + global-rank conversion -----------------------------
// Per 256-bucket block: (a) grank[abs] = uniqueOff[lo] + hrank (coalesced-ish),
// (b) stage unique (lo,hi) into LDS, emit verts one-thread-per-vertex.
__global__ __launch_bounds__(SB) void k_verts(
    const int* __restrict__ bucketOff, const int* __restrict__ bucketCnt,
    const int* __restrict__ uniqueOff, const int* __restrict__ uniqueCnt,
    const unsigned* __restrict__ edges32, const unsigned short* __restrict__ hrankArr,
    unsigned* __restrict__ grank,
    const float* __restrict__ pos, const float* __restrict__ sdf,
    float* __restrict__ out, int nv) {
  __shared__ unsigned shHi[SORT_LDS];
  __shared__ unsigned shLo[SORT_LDS];
  int v0 = blockIdx.x * SB;
  int vLast = v0 + SB - 1;
  if (vLast >= nv) vLast = nv - 1;
  int Ustart = uniqueOff[v0];
  int Utot = uniqueOff[vLast] + uniqueCnt[vLast] - Ustart;
  int v = v0 + threadIdx.x;
  int n = (v < nv) ? bucketCnt[v] : 0;
  int u = (v < nv) ? uniqueCnt[v] : 0;
  int boff = (v < nv) ? bucketOff[v] : 0;
  int uoff = (v < nv) ? uniqueOff[v] : 0;
  int lofs = uoff - Ustart;
  for (int k = 0; k < n; k++) grank[boff + k] = (unsigned)(uoff + (int)hrankArr[boff + k]);
  if (Utot <= SORT_LDS) {
    for (int k = 0; k < u; k++) { shHi[lofs + k] = edges32[boff + k]; shLo[lofs + k] = (unsigned)v; }
    __syncthreads();
    for (int i = threadIdx.x; i < Utot; i += SB) {
      int lo = (int)shLo[i];
      int hi = (int)shHi[i];
      float s0 = sdf[lo];
      float ns1 = -sdf[hi];
      float denom = s0 + ns1;          // matches reference s.sum(1)
      float w0 = ns1 / denom;
      float w1 = s0 / denom;
      int r = Ustart + i;
      out[3 * r + 0] = pos[3 * lo + 0] * w0 + pos[3 * hi + 0] * w1;
      out[3 * r + 1] = pos[3 * lo + 1] * w0 + pos[3 * hi + 1] * w1;
      out[3 * r + 2] = pos[3 * lo + 2] * w0 + pos[3 * hi + 2] * w1;
    }
  } else {
    // correctness fallback: direct per-bucket emit
    for (int k = 0; k < u; k++) {
      int lo = v;
      int hi = (int)edges32[boff + k];
      float s0 = sdf[lo];
      float ns1 = -sdf[hi];
      float denom = s0 + ns1;
      float w0 = ns1 / denom;
      float w1 = s0 / denom;
      int r = uoff + k;
      out[3 * r + 0] = pos[3 * lo + 0] * w0 + pos[3 * hi + 0] * w1;
      out[3 * r + 1] = pos[3 * lo + 1] * w0 + pos[3 * hi + 1] * w1;
      out[3 * r + 2] = pos[3 * lo + 2] * w0 + pos[3 * hi + 2] * w1;
    }
  }
}

// ---------------- faces + uv_idx (dense writes; single u32 gather per edge) --
__global__ void k_face(const uint8_t* __restrict__ tetidx,
                       const unsigned long long* __restrict__ tetRank, const int* __restrict__ scal,
                       const int4* __restrict__ stashAbs, const unsigned* __restrict__ grank,
                       float* __restrict__ out, int nt) {
  int t = blockIdx.x * blockDim.x + threadIdx.x;
  if (t >= nt) return;
  int bits = tetidx[t];
  int nt3 = c_ntri[bits];
  if (nt3 == 0) return;
  int4 sabs = stashAbs[t];
  int sa[4] = {sabs.x, sabs.y, sabs.z, sabs.w};
  int rk[6];
  int c = 0;
#pragma unroll
  for (int e = 0; e < 6; e++) {
    int a = c_ea[e], b = c_eb[e];
    if ((((bits >> a) ^ (bits >> b)) & 1) == 0) continue;
    rk[e] = (int)grank[sa[c++]];
  }
  unsigned long long pk = tetRank[t];
  int M1 = scal[0], facesOff = scal[4], uvidxOff = scal[6];
  int row = (nt3 == 1) ? (int)(pk & 0xffffffffull) : M1 + 2 * (int)(pk >> 32);
  float* f = out + facesOff + (size_t)3 * row;
  int npos = 3 * nt3;
  for (int p = 0; p < npos; p++) f[p] = (float)rk[c_tri[bits][p]];
  float* o = out + uvidxOff + (size_t)3 * row;
  float bt4 = (float)(4 * t);
  o[0] = bt4; o[1] = bt4 + 1.0f; o[2] = bt4 + 2.0f;
  if (nt3 == 2) { o[3] = bt4; o[4] = bt4 + 2.0f; o[5] = bt4 + 3.0f; }
}

// ---------------- uvs --------------------------------------------------------
__global__ void k_uvs(const int* __restrict__ scal, float* __restrict__ out, int N) {
  int i = blockIdx.x * blockDim.x + threadIdx.x;
  int total = N * N;
  if (i >= total) return;
  int ty = i / N, tx = i - ty * N;
  float x = (float)tx / (float)N;
  float y = (float)ty / (float)N;
  float pad = (float)(0.9 / (double)N);
  float* o = out + scal[5] + (size_t)i * 8;
  o[0] = x;       o[1] = y;
  o[2] = x + pad; o[3] = y;
  o[4] = x + pad; o[5] = y + pad;
  o[6] = x;       o[7] = y + pad;
}

extern "C" void kernel_launch(void* const* d_in, const int* in_sizes, int n_in,
                              void* d_out, int out_size, void* d_ws, size_t ws_size,
                              hipStream_t stream) {
  const float* pos = (const float*)d_in[0];
  const float* sdf = (const float*)d_in[1];
  const int* tet = (const int*)d_in[2];
  int nv = in_sizes[1];
  int nt = in_sizes[2] / 4;

  // workspace layout (256B aligned slices)
  char* w = (char*)d_ws;
  size_t off = 0;
  auto A = [&](size_t bytes) -> char* {
    off = (off + 255) & ~(size_t)255;
    char* p = w + off;
    off += bytes;
    return p;
  };
  int* scal = (int*)A(64 * sizeof(int));
  uint8_t* tetidx = (uint8_t*)A((size_t)nt);
  unsigned long long* tetRank = (unsigned long long*)A((size_t)nt * 8);
  int* bucketCnt = (int*)A((size_t)nv * 4);
  int* bucketOff = (int*)A((size_t)nv * 4);
  int* uniqueCnt = (int*)A((size_t)nv * 4);
  int* uniqueOff = (int*)A((size_t)nv * 4);
  ushort4* stash = (ushort4*)A((size_t)nt * 8);
  int4* stashAbs = (int4*)A((size_t)nt * 16);
  unsigned short* hrankArr = (unsigned short*)A((size_t)nt * 4 * 2);
  unsigned* grank = (unsigned*)A((size_t)nt * 4 * 4);
  unsigned* edges32 = (unsigned*)A((size_t)nt * 4 * 4);   // <=4 crossing edges/tet
  unsigned long long* blockTotU = (unsigned long long*)A(8 * 4096);
  int* blockTotI = (int*)A(4 * 4096);

  hipMemsetAsync(bucketCnt, 0, (size_t)nv * 4, stream);

  int nb_t = (nt + SCHUNK - 1) / SCHUNK;
  int nb_v = (nv + SCHUNK - 1) / SCHUNK;
  int nbv_sort = (nv + SB - 1) / SB;

  k_classify<<<(nt + 255) / 256, 256, 0, stream>>>((const int4*)tet, sdf, tetidx, bucketCnt,
                                                   stash, nt);

  k_tetscan1<<<nb_t, SB, 0, stream>>>(tetidx, blockTotU, nt);
  k_scanblk_u64<<<1, SB, 0, stream>>>(blockTotU, nb_t, scal, 0, 1);
  k_tetscan3<<<nb_t, SB, 0, stream>>>(tetidx, blockTotU, tetRank, nt);

  k_i32scan1<<<nb_v, SB, 0, stream>>>(bucketCnt, blockTotI, nv);
  k_scanblk_i32<<<1, SB, 0, stream>>>(blockTotI, nb_v, scal, 2);
  k_i32scan3<<<nb_v, SB, 0, stream>>>(bucketCnt, blockTotI, bucketOff, nv);

  k_scatter<<<(nt + 255) / 256, 256, 0, stream>>>((const int4*)tet, tetidx, bucketOff,
                                                  stash, edges32, stashAbs, nt);

  k_sortuniq<<<nbv_sort, SB, 0, stream>>>(bucketOff, bucketCnt, edges32, hrankArr,
                                          uniqueCnt, nv);

  k_i32scan1<<<nb_v, SB, 0, stream>>>(uniqueCnt, blockTotI, nv);
  k_scanblk_i32<<<1, SB, 0, stream>>>(blockTotI, nb_v, scal, 3);
  k_i32scan3<<<nb_v, SB, 0, stream>>>(uniqueCnt, blockTotI, uniqueOff, nv);

  long long maxidx = (long long)nt * 2;
  int N = (int)ceil(sqrt((double)((maxidx + 1) / 2)));
  int uvsElems = N * N * 8;

  k_offsets<<<1, 1, 0, stream>>>(scal, uvsElems);
  k_verts<<<nbv_sort, SB, 0, stream>>>(bucketOff, bucketCnt, uniqueOff, uniqueCnt,
                                       edges32, hrankArr, grank, pos, sdf, (float*)d_out, nv);
  k_face<<<(nt + 255) / 256, 256, 0, stream>>>(tetidx, tetRank, scal,
                                               stashAbs, grank, (float*)d_out, nt);
  k_uvs<<<(N * N + 255) / 256, 256, 0, stream>>>(scal, (float*)d_out, N);
}